// Round 10
// baseline (427.773 us; speedup 1.0000x reference)
//
#include <hip/hip_runtime.h>
#include <hip/hip_bf16.h>
#include <hip/hip_cooperative_groups.h>

namespace cg = cooperative_groups;

// ---------------------------------------------------------------------------
// LocalAttention: out = (softmax_mask(QK^T*s) V) Wo + bo, sliding causal W=256
// S=4096, D=1024, H=16, hd=64. bf16 MFMA (16x16x32), f32 accum.
// R10: cooperative mega-kernel, made robust after R9's silent launch failure
//      (grid=768 hard-coded at the exact occupancy edge -> TooLarge -> zeros):
//      (1) grid = occupancy-query x CUs (runtime's own math), persistent
//          loops tolerate any grid; (2) LDS 52224->35840 B via Ps-over-Qs
//          alias; (3) checked fallback to the proven R8 4-kernel path.
// Evidence log: QKV 2-barrier BK=32 128x128 is the K=1024 plateau (~44-47us;
//      R3/R5/R6/R7 structural variants all lost). Residual accounting:
//      ~44us harness ws-poison (fixed) + ~30-40us launch gaps (target here).
// ---------------------------------------------------------------------------

typedef __attribute__((ext_vector_type(8))) short bf16x8;
typedef __attribute__((ext_vector_type(4))) float f32x4;

#define S_LEN 4096
#define D_MODEL 1024
#define N_HEADS 16
#define HEAD_DIM 64
#define WINDOW 256
#define QKV_LD 3072

// attn LDS layout (bytes): [Qs|Ps alias 18432][Ks 8192][Vt 9216] = 35840
#define ATTN_LDS 35840

static __device__ __forceinline__ unsigned short f2bfbits(float f) {
    __hip_bfloat16 h = __float2bfloat16(f);
    unsigned short u;
    __builtin_memcpy(&u, &h, sizeof(u));
    return u;
}

typedef const __attribute__((address_space(1))) void c_gvoid;
typedef __attribute__((address_space(3))) void lvoid;
static __device__ __forceinline__ void gload16(const void* g, void* l) {
    __builtin_amdgcn_global_load_lds((c_gvoid*)g, (lvoid*)l, 16, 0, 0);
}

// ---------------- device GEMM tile: C[M][N] = A*Bt^T + bias -----------------
// R2 core: BK=32, unpadded 64B LDS rows, gload16 staging, 2-barrier K-loop.
// Swapped MFMA operands -> lane's 4 acc elems = 4 consecutive N-cols.
template <int TM, int TN, bool OUT_BF16>
static __device__ __forceinline__ void gemm_tile(char* smem,
                                                 const __hip_bfloat16* __restrict__ A,
                                                 const __hip_bfloat16* __restrict__ Bt,
                                                 const float* __restrict__ bias,
                                                 void* __restrict__ Cout,
                                                 int m0, int n0, int N, int K) {
    constexpr int MI = TM / 32;
    constexpr int NI = TN / 32;
    __hip_bfloat16* As = (__hip_bfloat16*)smem;          // TM*32 elems
    __hip_bfloat16* Bs = As + TM * 32;                   // TN*32 elems

    const int t = threadIdx.x;
    const int wave = t >> 6, lane = t & 63;
    const int quad = lane >> 4, l16 = lane & 15;
    const int wm = (wave & 1) * (TM / 2), wn = (wave >> 1) * (TN / 2);

    const int srow = t >> 2;           // 0..63
    const int scol = (t & 3) * 8;      // 0,8,16,24

    f32x4 acc[MI][NI];
#pragma unroll
    for (int mi = 0; mi < MI; ++mi)
#pragma unroll
        for (int ni = 0; ni < NI; ++ni) acc[mi][ni] = (f32x4){0.f, 0.f, 0.f, 0.f};

    const __hip_bfloat16* gA = A + (size_t)(m0 + srow) * K + scol;
    const __hip_bfloat16* gB = Bt + (size_t)(n0 + srow) * K + scol;

    for (int k0 = 0; k0 < K; k0 += 32) {
#pragma unroll
        for (int p = 0; p < TM / 64; ++p)
            gload16(gA + (size_t)(p * 64) * K + k0, &As[p * 2048 + t * 8]);
#pragma unroll
        for (int p = 0; p < TN / 64; ++p)
            gload16(gB + (size_t)(p * 64) * K + k0, &Bs[p * 2048 + t * 8]);
        __syncthreads();

        bf16x8 af[MI], bfr[NI];
#pragma unroll
        for (int mi = 0; mi < MI; ++mi)
            af[mi] = *(const bf16x8*)&As[(wm + mi * 16 + l16) * 32 + quad * 8];
#pragma unroll
        for (int ni = 0; ni < NI; ++ni)
            bfr[ni] = *(const bf16x8*)&Bs[(wn + ni * 16 + l16) * 32 + quad * 8];
#pragma unroll
        for (int mi = 0; mi < MI; ++mi)
#pragma unroll
            for (int ni = 0; ni < NI; ++ni)
                acc[mi][ni] = __builtin_amdgcn_mfma_f32_16x16x32_bf16(
                    bfr[ni], af[mi], acc[mi][ni], 0, 0, 0);
        __syncthreads();
    }

    float4 bv[NI];
#pragma unroll
    for (int ni = 0; ni < NI; ++ni)
        bv[ni] = *(const float4*)&bias[n0 + wn + ni * 16 + quad * 4];
#pragma unroll
    for (int mi = 0; mi < MI; ++mi) {
        const int row = m0 + wm + mi * 16 + l16;
#pragma unroll
        for (int ni = 0; ni < NI; ++ni) {
            const int col = n0 + wn + ni * 16 + quad * 4;
            if (OUT_BF16) {
                ushort4 o;
                o.x = f2bfbits(acc[mi][ni][0] + bv[ni].x);
                o.y = f2bfbits(acc[mi][ni][1] + bv[ni].y);
                o.z = f2bfbits(acc[mi][ni][2] + bv[ni].z);
                o.w = f2bfbits(acc[mi][ni][3] + bv[ni].w);
                *(ushort4*)((unsigned short*)Cout + (size_t)row * N + col) = o;
            } else {
                float4 o;
                o.x = acc[mi][ni][0] + bv[ni].x;
                o.y = acc[mi][ni][1] + bv[ni].y;
                o.z = acc[mi][ni][2] + bv[ni].z;
                o.w = acc[mi][ni][3] + bv[ni].w;
                *(float4*)((float*)Cout + (size_t)row * N + col) = o;
            }
        }
    }
}

// ---------------- device attention tile: 1 head x 128 queries ---------------
// 6 key tiles of 64 cover [i0-256, i0+128). Lane owns q rows rq0, rq0+16.
// Ps ALIASES Qs (Qs dead after aq regs loaded; the first in-loop barrier
// orders every wave's aq-load before any Ps write). LDS = 35840 B.
static __device__ __forceinline__ void attn_tile(char* smem,
                                                 const __hip_bfloat16* __restrict__ QKV,
                                                 __hip_bfloat16* __restrict__ AO,
                                                 int h, int i0) {
    __hip_bfloat16* Qs = (__hip_bfloat16*)smem;               // 128*64 (16 KB)
    __hip_bfloat16* Ps = (__hip_bfloat16*)smem;               // 128*72 (18 KB) alias
    __hip_bfloat16* Ks = (__hip_bfloat16*)(smem + 18432);     // 64*64  (8 KB)
    __hip_bfloat16* Vt = (__hip_bfloat16*)(smem + 18432 + 8192);  // 64*72 (9 KB)

    const int t = threadIdx.x;
    const int wave = t >> 6, lane = t & 63;
    const int quad = lane >> 4, l16 = lane & 15;
    const float sc = 0.125f * 1.44269504088896f;  // 1/sqrt(64) * log2(e)

    const __hip_bfloat16* Q = QKV + h * HEAD_DIM;
    const __hip_bfloat16* K = QKV + D_MODEL + h * HEAD_DIM;
    const __hip_bfloat16* V = QKV + 2 * D_MODEL + h * HEAD_DIM;

    const int grow = t >> 3;                       // 0..31
    const int glog = ((t & 7) ^ ((t >> 3) & 7)) * 8;
#pragma unroll
    for (int p = 0; p < 4; ++p)
        gload16(Q + (size_t)(i0 + p * 32 + grow) * QKV_LD + glog,
                &Qs[p * 2048 + t * 8]);
    __syncthreads();

    const int rq0 = wave * 32 + l16;     // lane's two q rows: rq0, rq0+16
    bf16x8 aq[2][2];
#pragma unroll
    for (int m = 0; m < 2; ++m) {
        const int rq = rq0 + m * 16;
#pragma unroll
        for (int kk = 0; kk < 2; ++kk)
            aq[m][kk] = *(const bf16x8*)&Qs[rq * 64 + ((kk * 4 + quad) ^ (rq & 7)) * 8];
    }

    float m_i[2] = {-3.0e38f, -3.0e38f}, l_i[2] = {0.f, 0.f};
    f32x4 Ov[2][4];
#pragma unroll
    for (int m = 0; m < 2; ++m)
#pragma unroll
        for (int no = 0; no < 4; ++no) Ov[m][no] = (f32x4){0.f, 0.f, 0.f, 0.f};

    const int vp = t >> 3, vc = t & 7;

    for (int tt = 0; tt < 6; ++tt) {
        const int tb = i0 - WINDOW + tt * 64;
        if (tb < 0) continue;  // uniform across block

#pragma unroll
        for (int p = 0; p < 2; ++p)
            gload16(K + (size_t)(tb + p * 32 + grow) * QKV_LD + glog,
                    &Ks[p * 2048 + t * 8]);
        {
            uint4 v0 = *(const uint4*)(V + (size_t)(tb + 2 * vp) * QKV_LD + vc * 8);
            uint4 v1 = *(const uint4*)(V + (size_t)(tb + 2 * vp + 1) * QKV_LD + vc * 8);
            const unsigned short* a0 = (const unsigned short*)&v0;
            const unsigned short* a1 = (const unsigned short*)&v1;
#pragma unroll
            for (int j = 0; j < 8; ++j) {
                unsigned int pk = (unsigned int)a0[j] | ((unsigned int)a1[j] << 16);
                *(unsigned int*)&Vt[(vc * 8 + j) * 72 + 2 * vp] = pk;
            }
        }
        __syncthreads();   // also orders all aq-loads before first Ps write

        f32x4 s[2][4];
#pragma unroll
        for (int m = 0; m < 2; ++m)
#pragma unroll
            for (int ni = 0; ni < 4; ++ni) s[m][ni] = (f32x4){0.f, 0.f, 0.f, 0.f};
#pragma unroll
        for (int kk = 0; kk < 2; ++kk)
#pragma unroll
            for (int ni = 0; ni < 4; ++ni) {
                int rk = ni * 16 + l16;
                bf16x8 bk = *(const bf16x8*)&Ks[rk * 64 + ((kk * 4 + quad) ^ (rk & 7)) * 8];
#pragma unroll
                for (int m = 0; m < 2; ++m)
                    s[m][ni] = __builtin_amdgcn_mfma_f32_16x16x32_bf16(
                        bk, aq[m][kk], s[m][ni], 0, 0, 0);
            }

        const int mode = (tt <= 1) ? 0 : ((tt >= 4) ? 2 : 1);
#pragma unroll
        for (int m = 0; m < 2; ++m) {
            const int qi = i0 + rq0 + m * 16;
            float mx = -3.0e38f;
#pragma unroll
            for (int ni = 0; ni < 4; ++ni)
#pragma unroll
                for (int r = 0; r < 4; ++r) {
                    int j = tb + ni * 16 + quad * 4 + r;
                    float v = s[m][ni][r] * sc;
                    if (mode == 0) v = (qi - j < WINDOW) ? v : -3.0e38f;
                    else if (mode == 2) v = (j <= qi) ? v : -3.0e38f;
                    s[m][ni][r] = v;
                    mx = fmaxf(mx, v);
                }
            mx = fmaxf(mx, __shfl_xor(mx, 16));
            mx = fmaxf(mx, __shfl_xor(mx, 32));
            const float mn = fmaxf(m_i[m], mx);
            const float alpha = exp2f(m_i[m] - mn);
            m_i[m] = mn;
            float sum = 0.f;
#pragma unroll
            for (int ni = 0; ni < 4; ++ni)
#pragma unroll
                for (int r = 0; r < 4; ++r) {
                    float e = exp2f(s[m][ni][r] - mn);
                    s[m][ni][r] = e;
                    sum += e;
                }
            sum += __shfl_xor(sum, 16);
            sum += __shfl_xor(sum, 32);
            l_i[m] = l_i[m] * alpha + sum;
#pragma unroll
            for (int no = 0; no < 4; ++no) Ov[m][no] *= alpha;

            const int rq = rq0 + m * 16;
#pragma unroll
            for (int ni = 0; ni < 4; ++ni) {
                ushort4 w4;
                w4.x = f2bfbits(s[m][ni][0]); w4.y = f2bfbits(s[m][ni][1]);
                w4.z = f2bfbits(s[m][ni][2]); w4.w = f2bfbits(s[m][ni][3]);
                *(ushort4*)&Ps[rq * 72 + ni * 16 + quad * 4] = w4;
            }
        }

#pragma unroll
        for (int kk = 0; kk < 2; ++kk) {
            bf16x8 ap[2];
#pragma unroll
            for (int m = 0; m < 2; ++m)
                ap[m] = *(const bf16x8*)&Ps[(rq0 + m * 16) * 72 + kk * 32 + quad * 8];
#pragma unroll
            for (int no = 0; no < 4; ++no) {
                bf16x8 bvv = *(const bf16x8*)&Vt[(no * 16 + l16) * 72 + kk * 32 + quad * 8];
#pragma unroll
                for (int m = 0; m < 2; ++m)
                    Ov[m][no] = __builtin_amdgcn_mfma_f32_16x16x32_bf16(
                        bvv, ap[m], Ov[m][no], 0, 0, 0);
            }
        }
        __syncthreads();
    }

#pragma unroll
    for (int m = 0; m < 2; ++m) {
        const float inv = 1.0f / l_i[m];
        const int qi = i0 + rq0 + m * 16;
#pragma unroll
        for (int no = 0; no < 4; ++no) {
            ushort4 o;
            o.x = f2bfbits(Ov[m][no][0] * inv);
            o.y = f2bfbits(Ov[m][no][1] * inv);
            o.z = f2bfbits(Ov[m][no][2] * inv);
            o.w = f2bfbits(Ov[m][no][3] * inv);
            *(ushort4*)((unsigned short*)AO + (size_t)qi * D_MODEL + h * HEAD_DIM +
                        no * 16 + quad * 4) = o;
        }
    }
}

// ---------------- prep work-unit (shared by mega + fallback) ----------------
static __device__ __forceinline__ void prep_unit(char* smem, int u, int t,
                                                 const float* __restrict__ x,
                                                 const float* __restrict__ Wq,
                                                 const float* __restrict__ Wk,
                                                 const float* __restrict__ Wv,
                                                 const float* __restrict__ Wo,
                                                 const float* __restrict__ bq,
                                                 const float* __restrict__ bk,
                                                 const float* __restrict__ bv,
                                                 unsigned short* __restrict__ xb,
                                                 __hip_bfloat16* __restrict__ Wqkvt,
                                                 __hip_bfloat16* __restrict__ Wot,
                                                 float* __restrict__ bcat) {
    if (u < 1024) {
        size_t i = (size_t)u * 4096 + t * 16;
#pragma unroll
        for (int q = 0; q < 4; ++q) {
            float4 v = *(const float4*)(x + i + q * 4);
            ushort4 o;
            o.x = f2bfbits(v.x); o.y = f2bfbits(v.y);
            o.z = f2bfbits(v.z); o.w = f2bfbits(v.w);
            *(ushort4*)(xb + i + q * 4) = o;
        }
    } else if (u < 2048) {
        __syncthreads();  // guard smem reuse across persistent iterations
        __hip_bfloat16 (*tile)[65] = (__hip_bfloat16(*)[65])smem;
        const int unit = u - 1024;
        const int m = unit >> 8;
        const int tid = unit & 255;
        const int n0 = (tid & 15) * 64, k0 = (tid >> 4) * 64;
        const float* src = (m == 0) ? Wq : (m == 1) ? Wk : (m == 2) ? Wv : Wo;
        __hip_bfloat16* dst = (m < 3) ? (Wqkvt + (size_t)m * D_MODEL * D_MODEL) : Wot;
        for (int c = t; c < 1024; c += 256) {
            int r = c >> 4, c4 = (c & 15) * 4;
            float4 v = *(const float4*)(src + (size_t)(k0 + r) * D_MODEL + n0 + c4);
            tile[r][c4 + 0] = __float2bfloat16(v.x);
            tile[r][c4 + 1] = __float2bfloat16(v.y);
            tile[r][c4 + 2] = __float2bfloat16(v.z);
            tile[r][c4 + 3] = __float2bfloat16(v.w);
        }
        __syncthreads();
        for (int c = t; c < 1024; c += 256) {
            int rr = c >> 4, c4 = (c & 15) * 4;
            ushort4 o;
            unsigned short u0, u1, u2, u3;
            __builtin_memcpy(&u0, &tile[c4 + 0][rr], 2);
            __builtin_memcpy(&u1, &tile[c4 + 1][rr], 2);
            __builtin_memcpy(&u2, &tile[c4 + 2][rr], 2);
            __builtin_memcpy(&u3, &tile[c4 + 3][rr], 2);
            o.x = u0; o.y = u1; o.z = u2; o.w = u3;
            *(ushort4*)((unsigned short*)dst + (size_t)(n0 + rr) * D_MODEL + k0 + c4) = o;
        }
    } else {
        for (int c = t; c < 3 * D_MODEL; c += 256) {
            float v = (c < 1024) ? bq[c] : (c < 2048) ? bk[c - 1024] : bv[c - 2048];
            bcat[c] = v;
        }
    }
}

// ---------------- the mega kernel (persistent, any grid size) ---------------
__global__ __launch_bounds__(256, 3) void mega_k(const float* __restrict__ x,
                                                 const float* __restrict__ Wq,
                                                 const float* __restrict__ Wk,
                                                 const float* __restrict__ Wv,
                                                 const float* __restrict__ Wo,
                                                 const float* __restrict__ bq,
                                                 const float* __restrict__ bk,
                                                 const float* __restrict__ bv,
                                                 const float* __restrict__ bo,
                                                 float* __restrict__ out,
                                                 char* __restrict__ ws) {
    __shared__ __align__(16) char smem[ATTN_LDS];   // union: attn 35840 > gemm 16384

    const size_t MB = 1u << 20;
    unsigned short* xb      = (unsigned short*)(ws);            // 8 MB
    __hip_bfloat16* Wqkvt   = (__hip_bfloat16*)(ws + 8 * MB);   // 6 MB
    __hip_bfloat16* Wot     = (__hip_bfloat16*)(ws + 14 * MB);  // 2 MB
    float*          bcat    = (float*)(ws + 16 * MB);           // 12 KB
    __hip_bfloat16* QKV     = (__hip_bfloat16*)(ws + 17 * MB);  // 24 MB
    __hip_bfloat16* AO      = (__hip_bfloat16*)(ws + 41 * MB);  // 8 MB

    const int b = blockIdx.x;
    const int G = gridDim.x;
    const int t = threadIdx.x;
    cg::grid_group grid = cg::this_grid();

    // phase 0: x-cast (1024 units) + W transposes (1024) + bias (1)
    for (int u = b; u < 2049; u += G)
        prep_unit(smem, u, t, x, Wq, Wk, Wv, Wo, bq, bk, bv, xb, Wqkvt, Wot, bcat);
    __threadfence();
    grid.sync();

    // phase 1: fused QKV projection, 768 tiles of 128x128
    for (int u = b; u < 768; u += G)
        gemm_tile<128, 128, true>(smem, (const __hip_bfloat16*)xb, Wqkvt, bcat,
                                  QKV, (u / 24) * 128, (u % 24) * 128,
                                  QKV_LD, D_MODEL);
    __threadfence();
    grid.sync();

    // phase 2: attention, 512 units (32 q-tiles x 16 heads)
    for (int u = b; u < 512; u += G) {
        __syncthreads();
        attn_tile(smem, QKV, AO, u >> 5, (u & 31) * 128);
    }
    __threadfence();
    grid.sync();

    // phase 3: output projection, 512 tiles of 128x64
    for (int u = b; u < 512; u += G) {
        __syncthreads();
        gemm_tile<128, 64, false>(smem, AO, Wot, bo, out,
                                  (u >> 4) * 128, (u & 15) * 64,
                                  D_MODEL, D_MODEL);
    }
}

// ---------------- fallback kernels (R8 path) --------------------------------
__global__ __launch_bounds__(256) void prep_k(const float* __restrict__ x,
                                              const float* __restrict__ Wq,
                                              const float* __restrict__ Wk,
                                              const float* __restrict__ Wv,
                                              const float* __restrict__ Wo,
                                              const float* __restrict__ bq,
                                              const float* __restrict__ bk,
                                              const float* __restrict__ bv,
                                              unsigned short* __restrict__ xb,
                                              __hip_bfloat16* __restrict__ Wqkvt,
                                              __hip_bfloat16* __restrict__ Wot,
                                              float* __restrict__ bcat) {
    __shared__ __align__(16) char smem[8320];
    prep_unit(smem, blockIdx.x, threadIdx.x, x, Wq, Wk, Wv, Wo, bq, bk, bv,
              xb, Wqkvt, Wot, bcat);
}

__global__ __launch_bounds__(256) void qkv_k(const __hip_bfloat16* __restrict__ xb,
                                             const __hip_bfloat16* __restrict__ Wqkvt,
                                             const float* __restrict__ bcat,
                                             __hip_bfloat16* __restrict__ QKV) {
    __shared__ __align__(16) char smem[16384];
    gemm_tile<128, 128, true>(smem, xb, Wqkvt, bcat, QKV,
                              blockIdx.y * 128, blockIdx.x * 128, QKV_LD, D_MODEL);
}

__global__ __launch_bounds__(256) void attn_sep_k(const __hip_bfloat16* __restrict__ QKV,
                                                  __hip_bfloat16* __restrict__ AO) {
    __shared__ __align__(16) char smem[ATTN_LDS];
    attn_tile(smem, QKV, AO, blockIdx.y, blockIdx.x * 128);
}

__global__ __launch_bounds__(256) void wo_k(const __hip_bfloat16* __restrict__ AO,
                                            const __hip_bfloat16* __restrict__ Wot,
                                            const float* __restrict__ bo,
                                            float* __restrict__ out) {
    __shared__ __align__(16) char smem[12288];
    gemm_tile<128, 64, false>(smem, AO, Wot, bo, out,
                              blockIdx.y * 128, blockIdx.x * 64, D_MODEL, D_MODEL);
}

// ---------------------------------------------------------------------------
extern "C" void kernel_launch(void* const* d_in, const int* in_sizes, int n_in,
                              void* d_out, int out_size, void* d_ws, size_t ws_size,
                              hipStream_t stream) {
    const float* x  = (const float*)d_in[0];
    const float* Wq = (const float*)d_in[1];
    const float* Wk = (const float*)d_in[2];
    const float* Wv = (const float*)d_in[3];
    const float* Wo = (const float*)d_in[4];
    const float* bq = (const float*)d_in[5];
    const float* bk = (const float*)d_in[6];
    const float* bv = (const float*)d_in[7];
    const float* bo = (const float*)d_in[8];
    float* out = (float*)d_out;
    char* ws = (char*)d_ws;

    // derive the cooperative grid from the runtime's own occupancy math
    int dev = 0;
    (void)hipGetDevice(&dev);
    int cus = 0;
    (void)hipDeviceGetAttribute(&cus, hipDeviceAttributeMultiprocessorCount, dev);
    int perCU = 0;
    hipError_t qe = hipOccupancyMaxActiveBlocksPerMultiprocessor(
        &perCU, (const void*)mega_k, 256, 0);
    long grid = (long)perCU * (long)cus;
    if (grid > 768) grid = 768;

    hipError_t le = hipErrorUnknown;
    if (qe == hipSuccess && grid >= 256) {
        void* args[] = {(void*)&x,  (void*)&Wq, (void*)&Wk, (void*)&Wv, (void*)&Wo,
                        (void*)&bq, (void*)&bk, (void*)&bv, (void*)&bo,
                        (void*)&out, (void*)&ws};
        le = hipLaunchCooperativeKernel((const void*)mega_k,
                                        dim3((unsigned)grid), dim3(256),
                                        args, 0, stream);
    }
    if (le != hipSuccess) {
        // fallback: proven R8 multi-kernel path
        const size_t MB = 1u << 20;
        unsigned short* xb    = (unsigned short*)(ws);
        __hip_bfloat16* Wqkvt = (__hip_bfloat16*)(ws + 8 * MB);
        __hip_bfloat16* Wot   = (__hip_bfloat16*)(ws + 14 * MB);
        float*          bcat  = (float*)(ws + 16 * MB);
        __hip_bfloat16* QKV   = (__hip_bfloat16*)(ws + 17 * MB);
        __hip_bfloat16* AO    = (__hip_bfloat16*)(ws + 41 * MB);

        prep_k<<<2049, 256, 0, stream>>>(x, Wq, Wk, Wv, Wo, bq, bk, bv,
                                         xb, Wqkvt, Wot, bcat);
        dim3 gqkv(QKV_LD / 128, S_LEN / 128);
        qkv_k<<<gqkv, 256, 0, stream>>>((const __hip_bfloat16*)xb, Wqkvt, bcat, QKV);
        dim3 ag(S_LEN / 128, N_HEADS);
        attn_sep_k<<<ag, 256, 0, stream>>>(QKV, AO);
        dim3 go(D_MODEL / 64, S_LEN / 128);
        wo_k<<<go, 256, 0, stream>>>(AO, Wot, bo, out);
    }
}

// Round 11
// 171.946 us; speedup vs baseline: 2.4878x; 2.4878x over previous
//
#include <hip/hip_runtime.h>
#include <hip/hip_bf16.h>

// ---------------------------------------------------------------------------
// LocalAttention: out = (softmax_mask(QK^T*s) V) Wo + bo, sliding causal W=256
// S=4096, D=1024, H=16, hd=64. bf16 MFMA (16x16x32), f32 accum.
// R11: back to the 4-kernel path built ONLY from hardware-verified pieces,
//      with DISTINCT kernel names so rocprof finally separates Wo and attn:
//      qkv_k  = exact R2 GEMM interior (44.2us measured; unswapped MFMA,
//               scalar epilogue — R8's swapped variant cost +3us),
//      attn_k = R8's verified 128-query flash attention,
//      wo_k   = R8's verified 128x64 swapped/float4 GEMM,
//      prep_k = R8's verified prep.
// Evidence log: cooperative grid.sync on this stack costs 100s of us
//      (R10: mega 625us, MfmaUtil 2.6%) -> coop path abandoned. QKV
//      2-barrier BK=32 128x128 = K=1024 plateau (R3/R5/R6/R7 all lost).
//      dur_us includes ~44us harness ws-poison (fixed).
// ---------------------------------------------------------------------------

typedef __attribute__((ext_vector_type(8))) short bf16x8;
typedef __attribute__((ext_vector_type(4))) float f32x4;

#define S_LEN 4096
#define D_MODEL 1024
#define N_HEADS 16
#define HEAD_DIM 64
#define WINDOW 256
#define QKV_LD 3072

static __device__ __forceinline__ unsigned short f2bfbits(float f) {
    __hip_bfloat16 h = __float2bfloat16(f);
    unsigned short u;
    __builtin_memcpy(&u, &h, sizeof(u));
    return u;
}

typedef const __attribute__((address_space(1))) void c_gvoid;
typedef __attribute__((address_space(3))) void lvoid;
static __device__ __forceinline__ void gload16(const void* g, void* l) {
    __builtin_amdgcn_global_load_lds((c_gvoid*)g, (lvoid*)l, 16, 0, 0);
}

// ---------------- fused prep: x-cast, W transposes, bias concat (R8) --------
__global__ __launch_bounds__(256) void prep_k(const float* __restrict__ x,
                                              const float* __restrict__ Wq,
                                              const float* __restrict__ Wk,
                                              const float* __restrict__ Wv,
                                              const float* __restrict__ Wo,
                                              const float* __restrict__ bq,
                                              const float* __restrict__ bk,
                                              const float* __restrict__ bv,
                                              unsigned short* __restrict__ xb,
                                              __hip_bfloat16* __restrict__ Wqkvt,
                                              __hip_bfloat16* __restrict__ Wot,
                                              float* __restrict__ bias_cat) {
    const int b = blockIdx.x;
    const int t = threadIdx.x;
    if (b < 2048) {
        int i = b * 2048 + t * 8;
        float4 v0 = *(const float4*)(x + i);
        float4 v1 = *(const float4*)(x + i + 4);
        ushort4 o0, o1;
        o0.x = f2bfbits(v0.x); o0.y = f2bfbits(v0.y);
        o0.z = f2bfbits(v0.z); o0.w = f2bfbits(v0.w);
        o1.x = f2bfbits(v1.x); o1.y = f2bfbits(v1.y);
        o1.z = f2bfbits(v1.z); o1.w = f2bfbits(v1.w);
        *(ushort4*)(xb + i) = o0;
        *(ushort4*)(xb + i + 4) = o1;
        return;
    }
    if (b < 3072) {
        __shared__ __hip_bfloat16 tile[64][65];
        const int m = (b - 2048) >> 8;
        const int tid = (b - 2048) & 255;
        const int n0 = (tid & 15) * 64, k0 = (tid >> 4) * 64;
        const float* src = (m == 0) ? Wq : (m == 1) ? Wk : (m == 2) ? Wv : Wo;
        __hip_bfloat16* dst = (m < 3) ? (Wqkvt + (size_t)m * D_MODEL * D_MODEL) : Wot;
        for (int c = t; c < 1024; c += 256) {
            int r = c >> 4, c4 = (c & 15) * 4;
            float4 v = *(const float4*)(src + (size_t)(k0 + r) * D_MODEL + n0 + c4);
            tile[r][c4 + 0] = __float2bfloat16(v.x);
            tile[r][c4 + 1] = __float2bfloat16(v.y);
            tile[r][c4 + 2] = __float2bfloat16(v.z);
            tile[r][c4 + 3] = __float2bfloat16(v.w);
        }
        __syncthreads();
        for (int c = t; c < 1024; c += 256) {
            int rr = c >> 4, c4 = (c & 15) * 4;
            ushort4 o;
            unsigned short u0, u1, u2, u3;
            __builtin_memcpy(&u0, &tile[c4 + 0][rr], 2);
            __builtin_memcpy(&u1, &tile[c4 + 1][rr], 2);
            __builtin_memcpy(&u2, &tile[c4 + 2][rr], 2);
            __builtin_memcpy(&u3, &tile[c4 + 3][rr], 2);
            o.x = u0; o.y = u1; o.z = u2; o.w = u3;
            *(ushort4*)((unsigned short*)dst + (size_t)(n0 + rr) * D_MODEL + k0 + c4) = o;
        }
        return;
    }
    for (int c = t; c < 3 * D_MODEL; c += 256) {
        float v = (c < 1024) ? bq[c] : (c < 2048) ? bk[c - 1024] : bv[c - 2048];
        bias_cat[c] = v;
    }
}

// ---------------- QKV GEMM: exact R2 interior (measured 44.2us) -------------
// C[4096][3072] = xb[4096][1024] * Wqkvt[3072][1024]^T + bcat. 128x128, BK=32.
__global__ __launch_bounds__(256) void qkv_k(const __hip_bfloat16* __restrict__ A,
                                             const __hip_bfloat16* __restrict__ Bt,
                                             const float* __restrict__ bias,
                                             __hip_bfloat16* __restrict__ Cout) {
    constexpr int K = D_MODEL, N = QKV_LD;
    __shared__ __align__(16) __hip_bfloat16 As[128 * 32];
    __shared__ __align__(16) __hip_bfloat16 Bs[128 * 32];

    const int m0 = blockIdx.y * 128, n0 = blockIdx.x * 128;
    const int t = threadIdx.x;
    const int wave = t >> 6, lane = t & 63;
    const int quad = lane >> 4, l16 = lane & 15;
    const int wm = (wave & 1) * 64, wn = (wave >> 1) * 64;

    const int srow = t >> 2;           // 0..63
    const int scol = (t & 3) * 8;      // 0,8,16,24

    f32x4 acc[4][4];
#pragma unroll
    for (int mi = 0; mi < 4; ++mi)
#pragma unroll
        for (int ni = 0; ni < 4; ++ni) acc[mi][ni] = (f32x4){0.f, 0.f, 0.f, 0.f};

    const __hip_bfloat16* gA = A + (size_t)(m0 + srow) * K + scol;
    const __hip_bfloat16* gB = Bt + (size_t)(n0 + srow) * K + scol;
    const size_t strideA = (size_t)64 * K;

    for (int k0 = 0; k0 < K; k0 += 32) {
        gload16(gA + k0, &As[t * 8]);
        gload16(gA + k0 + strideA, &As[2048 + t * 8]);
        gload16(gB + k0, &Bs[t * 8]);
        gload16(gB + k0 + strideA, &Bs[2048 + t * 8]);
        __syncthreads();

        bf16x8 af[4], bfr[4];
#pragma unroll
        for (int mi = 0; mi < 4; ++mi)
            af[mi] = *(const bf16x8*)&As[(wm + mi * 16 + l16) * 32 + quad * 8];
#pragma unroll
        for (int ni = 0; ni < 4; ++ni)
            bfr[ni] = *(const bf16x8*)&Bs[(wn + ni * 16 + l16) * 32 + quad * 8];
#pragma unroll
        for (int mi = 0; mi < 4; ++mi)
#pragma unroll
            for (int ni = 0; ni < 4; ++ni)
                acc[mi][ni] = __builtin_amdgcn_mfma_f32_16x16x32_bf16(
                    af[mi], bfr[ni], acc[mi][ni], 0, 0, 0);
        __syncthreads();
    }

    // R2 epilogue: C row = quad*4+r, col = l16 (per 16x16 frag)
#pragma unroll
    for (int mi = 0; mi < 4; ++mi) {
#pragma unroll
        for (int ni = 0; ni < 4; ++ni) {
#pragma unroll
            for (int r = 0; r < 4; ++r) {
                int row = m0 + wm + mi * 16 + quad * 4 + r;
                int col = n0 + wn + ni * 16 + l16;
                float v = acc[mi][ni][r] + bias[col];
                Cout[(size_t)row * N + col] = __float2bfloat16(v);
            }
        }
    }
}

// ---------------- Wo GEMM: R8's 128x64 swapped/float4 (verified) ------------
__global__ __launch_bounds__(256) void wo_k(const __hip_bfloat16* __restrict__ A,
                                            const __hip_bfloat16* __restrict__ Bt,
                                            const float* __restrict__ bias,
                                            float* __restrict__ Cout) {
    constexpr int TM = 128, TN = 64, K = D_MODEL, N = D_MODEL;
    constexpr int MI = 4, NI = 2;
    __shared__ __align__(16) __hip_bfloat16 As[TM * 32];
    __shared__ __align__(16) __hip_bfloat16 Bs[TN * 32];

    const int m0 = blockIdx.y * TM, n0 = blockIdx.x * TN;
    const int t = threadIdx.x;
    const int wave = t >> 6, lane = t & 63;
    const int quad = lane >> 4, l16 = lane & 15;
    const int wm = (wave & 1) * (TM / 2), wn = (wave >> 1) * (TN / 2);

    const int srow = t >> 2;
    const int scol = (t & 3) * 8;

    f32x4 acc[MI][NI];
#pragma unroll
    for (int mi = 0; mi < MI; ++mi)
#pragma unroll
        for (int ni = 0; ni < NI; ++ni) acc[mi][ni] = (f32x4){0.f, 0.f, 0.f, 0.f};

    const __hip_bfloat16* gA = A + (size_t)(m0 + srow) * K + scol;
    const __hip_bfloat16* gB = Bt + (size_t)(n0 + srow) * K + scol;

    for (int k0 = 0; k0 < K; k0 += 32) {
#pragma unroll
        for (int p = 0; p < TM / 64; ++p)
            gload16(gA + (size_t)(p * 64) * K + k0, &As[p * 2048 + t * 8]);
        if (t < 128)  // TN/64 = 1 pass covers 64 rows; lanes t<128 stage 32 rows... 
            ;         // (kept uniform below instead)
        gload16(gB + k0, &Bs[t * 8 >= TN * 32 ? 0 : t * 8]);
        __syncthreads();

        bf16x8 af[MI], bfr[NI];
#pragma unroll
        for (int mi = 0; mi < MI; ++mi)
            af[mi] = *(const bf16x8*)&As[(wm + mi * 16 + l16) * 32 + quad * 8];
#pragma unroll
        for (int ni = 0; ni < NI; ++ni)
            bfr[ni] = *(const bf16x8*)&Bs[(wn + ni * 16 + l16) * 32 + quad * 8];
#pragma unroll
        for (int mi = 0; mi < MI; ++mi)
#pragma unroll
            for (int ni = 0; ni < NI; ++ni)
                acc[mi][ni] = __builtin_amdgcn_mfma_f32_16x16x32_bf16(
                    bfr[ni], af[mi], acc[mi][ni], 0, 0, 0);
        __syncthreads();
    }

    float4 bv[NI];
#pragma unroll
    for (int ni = 0; ni < NI; ++ni)
        bv[ni] = *(const float4*)&bias[n0 + wn + ni * 16 + quad * 4];
#pragma unroll
    for (int mi = 0; mi < MI; ++mi) {
        const int row = m0 + wm + mi * 16 + l16;
#pragma unroll
        for (int ni = 0; ni < NI; ++ni) {
            const int col = n0 + wn + ni * 16 + quad * 4;
            float4 o;
            o.x = acc[mi][ni][0] + bv[ni].x;
            o.y = acc[mi][ni][1] + bv[ni].y;
            o.z = acc[mi][ni][2] + bv[ni].z;
            o.w = acc[mi][ni][3] + bv[ni].w;
            *(float4*)(Cout + (size_t)row * N + col) = o;
        }
    }
}

// ---------------- sliding-window flash attention, 128-q blocks (R8) ---------
__global__ __launch_bounds__(256) void attn_k(const __hip_bfloat16* __restrict__ QKV,
                                              __hip_bfloat16* __restrict__ AO) {
    __shared__ __align__(16) __hip_bfloat16 Qs[128 * 64];   // 16 KB, XOR-8 rows
    __shared__ __align__(16) __hip_bfloat16 Ks[64 * 64];    // 8 KB, XOR-8 rows
    __shared__ __align__(16) __hip_bfloat16 Vt[64 * 72];    // [hd][key], padded
    __shared__ __align__(16) __hip_bfloat16 Ps[128 * 72];   // [q][key], padded

    const int h = blockIdx.y;
    const int i0 = blockIdx.x * 128;
    const int t = threadIdx.x;
    const int wave = t >> 6, lane = t & 63;
    const int quad = lane >> 4, l16 = lane & 15;
    const float sc = 0.125f * 1.44269504088896f;  // 1/sqrt(64) * log2(e)

    const __hip_bfloat16* Q = QKV + h * HEAD_DIM;
    const __hip_bfloat16* K = QKV + D_MODEL + h * HEAD_DIM;
    const __hip_bfloat16* V = QKV + 2 * D_MODEL + h * HEAD_DIM;

    const int grow = t >> 3;                       // 0..31
    const int glog = ((t & 7) ^ ((t >> 3) & 7)) * 8;
#pragma unroll
    for (int p = 0; p < 4; ++p)
        gload16(Q + (size_t)(i0 + p * 32 + grow) * QKV_LD + glog,
                &Qs[p * 2048 + t * 8]);
    __syncthreads();

    const int rq0 = wave * 32 + l16;     // lane's two q rows: rq0, rq0+16
    bf16x8 aq[2][2];
#pragma unroll
    for (int m = 0; m < 2; ++m) {
        const int rq = rq0 + m * 16;
#pragma unroll
        for (int kk = 0; kk < 2; ++kk)
            aq[m][kk] = *(const bf16x8*)&Qs[rq * 64 + ((kk * 4 + quad) ^ (rq & 7)) * 8];
    }

    float m_i[2] = {-3.0e38f, -3.0e38f}, l_i[2] = {0.f, 0.f};
    f32x4 Ov[2][4];
#pragma unroll
    for (int m = 0; m < 2; ++m)
#pragma unroll
        for (int no = 0; no < 4; ++no) Ov[m][no] = (f32x4){0.f, 0.f, 0.f, 0.f};

    const int vp = t >> 3, vc = t & 7;

    for (int tt = 0; tt < 6; ++tt) {
        const int tb = i0 - WINDOW + tt * 64;
        if (tb < 0) continue;  // uniform across block

#pragma unroll
        for (int p = 0; p < 2; ++p)
            gload16(K + (size_t)(tb + p * 32 + grow) * QKV_LD + glog,
                    &Ks[p * 2048 + t * 8]);
        {
            uint4 v0 = *(const uint4*)(V + (size_t)(tb + 2 * vp) * QKV_LD + vc * 8);
            uint4 v1 = *(const uint4*)(V + (size_t)(tb + 2 * vp + 1) * QKV_LD + vc * 8);
            const unsigned short* a0 = (const unsigned short*)&v0;
            const unsigned short* a1 = (const unsigned short*)&v1;
#pragma unroll
            for (int j = 0; j < 8; ++j) {
                unsigned int pk = (unsigned int)a0[j] | ((unsigned int)a1[j] << 16);
                *(unsigned int*)&Vt[(vc * 8 + j) * 72 + 2 * vp] = pk;
            }
        }
        __syncthreads();

        f32x4 s[2][4];
#pragma unroll
        for (int m = 0; m < 2; ++m)
#pragma unroll
            for (int ni = 0; ni < 4; ++ni) s[m][ni] = (f32x4){0.f, 0.f, 0.f, 0.f};
#pragma unroll
        for (int kk = 0; kk < 2; ++kk)
#pragma unroll
            for (int ni = 0; ni < 4; ++ni) {
                int rk = ni * 16 + l16;
                bf16x8 bk = *(const bf16x8*)&Ks[rk * 64 + ((kk * 4 + quad) ^ (rk & 7)) * 8];
#pragma unroll
                for (int m = 0; m < 2; ++m)
                    s[m][ni] = __builtin_amdgcn_mfma_f32_16x16x32_bf16(
                        bk, aq[m][kk], s[m][ni], 0, 0, 0);
            }

#pragma unroll
        for (int m = 0; m < 2; ++m) {
            const int qi = i0 + rq0 + m * 16;
            float mx = -3.0e38f;
#pragma unroll
            for (int ni = 0; ni < 4; ++ni)
#pragma unroll
                for (int r = 0; r < 4; ++r) {
                    int j = tb + ni * 16 + quad * 4 + r;
                    float v = s[m][ni][r] * sc;
                    bool ok = (j <= qi) && (qi - j < WINDOW);
                    v = ok ? v : -3.0e38f;
                    s[m][ni][r] = v;
                    mx = fmaxf(mx, v);
                }
            mx = fmaxf(mx, __shfl_xor(mx, 16));
            mx = fmaxf(mx, __shfl_xor(mx, 32));
            const float mn = fmaxf(m_i[m], mx);
            const float alpha = exp2f(m_i[m] - mn);
            m_i[m] = mn;
            float sum = 0.f;
#pragma unroll
            for (int ni = 0; ni < 4; ++ni)
#pragma unroll
                for (int r = 0; r < 4; ++r) {
                    float e = exp2f(s[m][ni][r] - mn);
                    s[m][ni][r] = e;
                    sum += e;
                }
            sum += __shfl_xor(sum, 16);
            sum += __shfl_xor(sum, 32);
            l_i[m] = l_i[m] * alpha + sum;
#pragma unroll
            for (int no = 0; no < 4; ++no) Ov[m][no] *= alpha;

            const int rq = rq0 + m * 16;
#pragma unroll
            for (int ni = 0; ni < 4; ++ni) {
                ushort4 w4;
                w4.x = f2bfbits(s[m][ni][0]); w4.y = f2bfbits(s[m][ni][1]);
                w4.z = f2bfbits(s[m][ni][2]); w4.w = f2bfbits(s[m][ni][3]);
                *(ushort4*)&Ps[rq * 72 + ni * 16 + quad * 4] = w4;
            }
        }

#pragma unroll
        for (int kk = 0; kk < 2; ++kk) {
            bf16x8 ap[2];
#pragma unroll
            for (int m = 0; m < 2; ++m)
                ap[m] = *(const bf16x8*)&Ps[(rq0 + m * 16) * 72 + kk * 32 + quad * 8];
#pragma unroll
            for (int no = 0; no < 4; ++no) {
                bf16x8 bvv = *(const bf16x8*)&Vt[(no * 16 + l16) * 72 + kk * 32 + quad * 8];
#pragma unroll
                for (int m = 0; m < 2; ++m)
                    Ov[m][no] = __builtin_amdgcn_mfma_f32_16x16x32_bf16(
                        bvv, ap[m], Ov[m][no], 0, 0, 0);
            }
        }
        __syncthreads();
    }

#pragma unroll
    for (int m = 0; m < 2; ++m) {
        const float inv = 1.0f / l_i[m];
        const int qi = i0 + rq0 + m * 16;
#pragma unroll
        for (int no = 0; no < 4; ++no) {
            ushort4 o;
            o.x = f2bfbits(Ov[m][no][0] * inv);
            o.y = f2bfbits(Ov[m][no][1] * inv);
            o.z = f2bfbits(Ov[m][no][2] * inv);
            o.w = f2bfbits(Ov[m][no][3] * inv);
            *(ushort4*)((unsigned short*)AO + (size_t)qi * D_MODEL + h * HEAD_DIM +
                        no * 16 + quad * 4) = o;
        }
    }
}

// ---------------------------------------------------------------------------
extern "C" void kernel_launch(void* const* d_in, const int* in_sizes, int n_in,
                              void* d_out, int out_size, void* d_ws, size_t ws_size,
                              hipStream_t stream) {
    const float* x  = (const float*)d_in[0];
    const float* Wq = (const float*)d_in[1];
    const float* Wk = (const float*)d_in[2];
    const float* Wv = (const float*)d_in[3];
    const float* Wo = (const float*)d_in[4];
    const float* bq = (const float*)d_in[5];
    const float* bk = (const float*)d_in[6];
    const float* bv = (const float*)d_in[7];
    const float* bo = (const float*)d_in[8];
    float* out = (float*)d_out;

    char* w = (char*)d_ws;
    const size_t MB = 1u << 20;
    __hip_bfloat16* xb    = (__hip_bfloat16*)(w + 0 * MB);   // 8 MB
    __hip_bfloat16* Wqkvt = (__hip_bfloat16*)(w + 8 * MB);   // 6 MB [3072][1024]
    __hip_bfloat16* Wot   = (__hip_bfloat16*)(w + 14 * MB);  // 2 MB
    float*          bcat  = (float*)(w + 16 * MB);           // 12 KB
    __hip_bfloat16* QKV   = (__hip_bfloat16*)(w + 17 * MB);  // 24 MB [4096][3072]
    __hip_bfloat16* AO    = (__hip_bfloat16*)(w + 41 * MB);  // 8 MB, end 49 MB

    prep_k<<<3073, 256, 0, stream>>>(x, Wq, Wk, Wv, Wo, bq, bk, bv,
                                     (unsigned short*)xb, Wqkvt, Wot, bcat);

    dim3 gqkv(QKV_LD / 128, S_LEN / 128);
    qkv_k<<<gqkv, 256, 0, stream>>>(xb, Wqkvt, bcat, QKV);

    dim3 ag(S_LEN / 128, N_HEADS);
    attn_k<<<ag, 256, 0, stream>>>(QKV, AO);

    dim3 go(D_MODEL / 64, S_LEN / 128);
    wo_k<<<go, 256, 0, stream>>>(AO, Wot, bo, out);
}